// Round 20
// baseline (154.135 us; speedup 1.0000x reference)
//
#include <hip/hip_runtime.h>

#define N_NODES 50000
#define N_EDGES 800000
#define NG      128
#define FIN     64
#define HD      108
#define CB2     196         // coarse blocks: ceil(800000/4096), 16 edges/thread
#define NBIN    98          // coarse bins: ceil(50000/512), 512 nodes/bin

typedef __attribute__((ext_vector_type(8))) short s16x8;   // 8 bf16 = 4 VGPRs
typedef __attribute__((ext_vector_type(4))) float f32x4;

__device__ __forceinline__ unsigned short bf16_rne(float x) {
    unsigned u = __float_as_uint(x);
    u += 0x7FFFu + ((u >> 16) & 1u);
    return (unsigned short)(u >> 16);
}
__device__ __forceinline__ float bf16_to_f(unsigned u16) {
    return __uint_as_float(u16 << 16);
}

// ---------------------------------------------------------------------------
// Fused prep. block ranges: [0,42) wprep | [42,56) gsum zero | [56] gcnt |
// [57,253) coarse LDS-histogram count (writes bb, bin-major, bin = d>>9)
// Weight tiles (24 kst x 7 nt): emb 0..1 | p1 2..5 | n1 6..12 | p2 13..16 | n2 17..23
// ---------------------------------------------------------------------------
__global__ void prep_k(const float* __restrict__ W0, const float* __restrict__ W1,
                       const float* __restrict__ W2, const float* __restrict__ W3,
                       const float* __restrict__ W4, unsigned short* __restrict__ Wf,
                       float* __restrict__ gsum,
                       const int* __restrict__ gids, int* __restrict__ gcnt,
                       const int* __restrict__ dst, int* __restrict__ bb) {
    int b = blockIdx.x, t = threadIdx.x;
    if (b < 42) {                                     // weight repack, 1 tile/wave
        int tile = b * 4 + (t >> 6), lane = t & 63;
        if (tile < 168) {
            int kst = tile / 7, nt = tile % 7;
            const float* W; int Kr, ks;
            if (kst < 2)       { W = W0; Kr = 64;  ks = kst;      }
            else if (kst < 6)  { W = W1; Kr = 108; ks = kst - 2;  }
            else if (kst < 13) { W = W2; Kr = 216; ks = kst - 6;  }
            else if (kst < 17) { W = W3; Kr = 108; ks = kst - 13; }
            else               { W = W4; Kr = 216; ks = kst - 17; }
            int n = nt * 16 + (lane & 15);
            s16x8 o;
            #pragma unroll
            for (int j = 0; j < 8; ++j) {
                int k = ks * 32 + (lane >> 4) * 8 + j;
                float v = (k < Kr && n < HD) ? W[k * HD + n] : 0.0f;
                o[j] = (short)bf16_rne(v);
            }
            *(s16x8*)(Wf + (size_t)tile * 512 + lane * 8) = o;
        }
    } else if (b < 56) {                              // gsum = 0
        int i = (b - 42) * 256 + t;
        if (i < NG * HD / 4) ((int4*)gsum)[i] = (int4){0, 0, 0, 0};
    } else if (b == 56) {                             // per-graph counts (sorted)
        int g = t;
        if (g < NG) {
            int lo = 0, hi = N_NODES;
            while (lo < hi) { int mid = (lo + hi) >> 1; if (gids[mid] < g) lo = mid + 1; else hi = mid; }
            int s = lo;
            lo = s; hi = N_NODES;
            while (lo < hi) { int mid = (lo + hi) >> 1; if (gids[mid] < g + 1) lo = mid + 1; else hi = mid; }
            gcnt[g] = lo - s;
        }
    } else {                                          // coarse count, 16 e/thread
        __shared__ int bins[NBIN];
        int cb = b - 57;
        if (t < NBIN) bins[t] = 0;
        __syncthreads();
        #pragma unroll
        for (int k = 0; k < 16; ++k) {
            int e = cb * 4096 + k * 256 + t;
            if (e < N_EDGES) atomicAdd(&bins[dst[e] >> 9], 1);
        }
        __syncthreads();
        if (t < NBIN) bb[t * CB2 + cb] = bins[t];
    }
}

// ---------------------------------------------------------------------------
// cscatter body: scatter packed (src | dlocal<<16) into coarse buckets.
// Cursors computed IN-BLOCK from bb (bin-major). No global atomics.
// ---------------------------------------------------------------------------
__device__ __forceinline__ void cscatter_body(
    int b, const int* __restrict__ src, const int* __restrict__ dst,
    const int* __restrict__ bb, unsigned* __restrict__ ebuf) {
    __shared__ int cur[NBIN];
    __shared__ int btot[NBIN];
    __shared__ int sc[128];
    int t = threadIdx.x;
    int myv = 0;
    if (t < NBIN) {                                   // thread t owns bin t
        int pre = 0, tot = 0;
        const int* row = bb + t * CB2;
        for (int b2 = 0; b2 < CB2; ++b2) {
            int v = row[b2];
            tot += v;
            if (b2 < b) pre += v;
        }
        btot[t] = tot;
        cur[t] = pre;                                 // within-bin offset
        myv = tot;
    }
    __syncthreads();
    if (t < 128) {                                    // 2-wave inclusive scan
        int v = (t < NBIN) ? btot[t] : 0;
        int x = v;
        #pragma unroll
        for (int off = 1; off < 64; off <<= 1) {
            int y = __shfl_up(x, off);
            if ((t & 63) >= off) x += y;
        }
        sc[t] = x;
    }
    __syncthreads();
    if (t < NBIN) {
        int incl = sc[t] + ((t >= 64) ? sc[63] : 0);
        cur[t] += incl - myv;                         // + exclusive bin start
    }
    __syncthreads();
    #pragma unroll
    for (int k = 0; k < 16; ++k) {
        int e = b * 4096 + k * 256 + t;
        if (e < N_EDGES) {
            int d = dst[e];
            int slot = atomicAdd(&cur[d >> 9], 1);
            ebuf[slot] = (unsigned)src[e] | ((unsigned)(d & 511) << 16);
        }
    }
}

// ---------------------------------------------------------------------------
// fine: per coarse bucket (<=512 nodes), 512 threads. Bucket [begin,end)
// computed in-block from bb. LDS histogram + scan -> rowp + csr scatter.
// ---------------------------------------------------------------------------
__global__ __launch_bounds__(512) void fine_k(
    const unsigned* __restrict__ ebuf, const int* __restrict__ bb,
    int* __restrict__ rowp, int* __restrict__ csr) {
    __shared__ int fb[512];
    __shared__ int s_w[8];
    __shared__ int red1[8], red2[8];
    int t = threadIdx.x, lane = t & 63, wid = t >> 6;
    int bin = blockIdx.x;

    // ---- compute begin/end from bb ----
    int lim1 = bin * CB2, lim2 = lim1 + CB2;
    int s1 = 0, s2 = 0;
    for (int i = t; i < lim2; i += 512) {
        int v = bb[i];
        if (i < lim1) s1 += v; else s2 += v;
    }
    #pragma unroll
    for (int off = 32; off >= 1; off >>= 1) {
        s1 += __shfl_xor(s1, off);
        s2 += __shfl_xor(s2, off);
    }
    if (lane == 0) { red1[wid] = s1; red2[wid] = s2; }
    __syncthreads();
    if (t == 0) {
        int a = 0, c = 0;
        #pragma unroll
        for (int w = 0; w < 8; ++w) { a += red1[w]; c += red2[w]; }
        red1[0] = a; red2[0] = c;
    }
    __syncthreads();
    int begin = red1[0], end = begin + red2[0];

    // ---- histogram over 512 local nodes ----
    fb[t] = 0;
    __syncthreads();
    for (int i = begin + t; i < end; i += 512)
        atomicAdd(&fb[ebuf[i] >> 16], 1);
    __syncthreads();
    int v = fb[t];
    int x = v;
    #pragma unroll
    for (int off = 1; off < 64; off <<= 1) {
        int y = __shfl_up(x, off);
        if (lane >= off) x += y;
    }
    if (lane == 63) s_w[wid] = x;
    __syncthreads();
    if (t < 8) {
        int y = s_w[t];
        #pragma unroll
        for (int off = 1; off < 8; off <<= 1) {
            int z = __shfl_up(y, off);
            if (t >= off) y += z;
        }
        s_w[t] = y;
    }
    __syncthreads();
    int ex = (wid ? s_w[wid - 1] : 0) + x - v;        // exclusive within bucket
    int node = bin * 512 + t;
    if (node < N_NODES) rowp[node] = begin + ex;
    if (bin == NBIN - 1 && t == 0) rowp[N_NODES] = N_EDGES;
    __syncthreads();
    fb[t] = ex;                                       // reuse as cursor
    __syncthreads();
    for (int i = begin + t; i < end; i += 512) {
        unsigned p = ebuf[i];
        int slot = atomicAdd(&fb[p >> 16], 1);
        csr[begin + slot] = (int)(p & 0xFFFFu);
    }
}

// ---------------------------------------------------------------------------
// Shared GEMM body. One wave = 16 nodes x 112 cols.
// EPI: 0=embed+pool, 2=apply+pool, 3=apply-final(graph-sum atomics).
// AF32: A operand is f32 (feat) -> convert to bf16 in-register.
// For EPI!=0, A-fragments ks<4 are staged into s_t for the LDS residual read.
// Epilogue maintains the hc col-216..223 zero pad (seg 14).
// m layout: CHUNKED m[ch][node][32] bf16, ch = col/32.
// ---------------------------------------------------------------------------
template <int KSTEPS, int EPI, bool AF32>
__device__ __forceinline__ void gemm_body(
    int blk,
    const void* __restrict__ Aptr, int strideA,
    const unsigned short* __restrict__ Wf, const float* __restrict__ bias,
    const unsigned short* __restrict__ Wfp, const float* __restrict__ biasp,
    unsigned short* __restrict__ hc, unsigned short* __restrict__ m_out,
    const int* __restrict__ gids, float* __restrict__ gsum) {
    __shared__ unsigned short s_t[4][16][136];
    int t = threadIdx.x, lane = t & 63, wave = t >> 6;
    int wrow = (blk * 4 + wave) * 16;
    if (wrow < N_NODES) {
        int l15 = lane & 15, lg = lane >> 4;

        f32x4 acc[7];
        #pragma unroll
        for (int nt = 0; nt < 7; ++nt) acc[nt] = (f32x4){0.f, 0.f, 0.f, 0.f};

        #pragma unroll
        for (int ks = 0; ks < KSTEPS; ++ks) {
            s16x8 a;
            if (AF32) {
                const float* arow = (const float*)Aptr + (size_t)(wrow + l15) * strideA + lg * 8 + ks * 32;
                float4 f0 = *(const float4*)arow;
                float4 f1 = *(const float4*)(arow + 4);
                a[0] = (short)bf16_rne(f0.x); a[1] = (short)bf16_rne(f0.y);
                a[2] = (short)bf16_rne(f0.z); a[3] = (short)bf16_rne(f0.w);
                a[4] = (short)bf16_rne(f1.x); a[5] = (short)bf16_rne(f1.y);
                a[6] = (short)bf16_rne(f1.z); a[7] = (short)bf16_rne(f1.w);
            } else {
                const unsigned short* arow = (const unsigned short*)Aptr + (size_t)(wrow + l15) * strideA + lg * 8;
                a = *(const s16x8*)(arow + ks * 32);
            }
            if (EPI != 0 && ks < 4)                   // stage h for residual
                *(s16x8*)&s_t[wave][l15][ks * 32 + lg * 8] = a;
            const unsigned short* wp = Wf + ((size_t)(ks * 7) * 64 + lane) * 8;
            #pragma unroll
            for (int nt = 0; nt < 7; ++nt) {
                s16x8 bfr = *(const s16x8*)(wp + (size_t)nt * 512);
                acc[nt] = __builtin_amdgcn_mfma_f32_16x16x32_bf16(a, bfr, acc[nt], 0, 0, 0);
            }
        }

        // D layout: col = nt*16 + l15, row(local) = lg*4 + r
        float vals[7][4];
        if (EPI == 0) {                               // embed: + bias
            #pragma unroll
            for (int nt = 0; nt < 7; ++nt) {
                int col = nt * 16 + l15;
                float bv = (col < HD) ? bias[col] : 0.0f;
                #pragma unroll
                for (int r = 0; r < 4; ++r) vals[nt][r] = acc[nt][r] + bv;
            }
        } else {                                      // apply: norm + residual
            float ss[4] = {0.f, 0.f, 0.f, 0.f};
            #pragma unroll
            for (int nt = 0; nt < 7; ++nt) {
                int col = nt * 16 + l15;
                bool valid = (col < HD);
                float bv = valid ? bias[col] : 0.0f;
                #pragma unroll
                for (int r = 0; r < 4; ++r) {
                    float v = valid ? (acc[nt][r] + bv) : 0.0f;
                    vals[nt][r] = v;
                    ss[r] += v * v;
                }
            }
            #pragma unroll
            for (int r = 0; r < 4; ++r) {
                ss[r] += __shfl_xor(ss[r], 1);
                ss[r] += __shfl_xor(ss[r], 2);
                ss[r] += __shfl_xor(ss[r], 4);
                ss[r] += __shfl_xor(ss[r], 8);
            }
            float rn[4];
            #pragma unroll
            for (int r = 0; r < 4; ++r) rn[r] = 1.0f / fmaxf(sqrtf(ss[r]), 1e-12f);
            #pragma unroll
            for (int nt = 0; nt < 7; ++nt) {
                int col = nt * 16 + l15;
                bool valid = (col < HD);
                #pragma unroll
                for (int r = 0; r < 4; ++r) {
                    float hv = valid ? bf16_to_f(s_t[wave][lg * 4 + r][col]) : 0.0f;
                    vals[nt][r] = hv + fmaxf(vals[nt][r] * rn[r], 0.0f);
                }
            }
        }

        if (EPI == 3) {                               // graph-mean accumulation
            int g0 = gids[wrow], g15 = gids[wrow + 15];
            if (g0 == g15) {
                #pragma unroll
                for (int nt = 0; nt < 7; ++nt) {
                    int col = nt * 16 + l15;
                    float cs = vals[nt][0] + vals[nt][1] + vals[nt][2] + vals[nt][3];
                    cs += __shfl_xor(cs, 16);
                    cs += __shfl_xor(cs, 32);
                    if (lane < 16 && col < HD) atomicAdd(&gsum[g0 * HD + col], cs);
                }
            } else {
                int gr[4];
                #pragma unroll
                for (int r = 0; r < 4; ++r) gr[r] = gids[wrow + lg * 4 + r];
                #pragma unroll
                for (int nt = 0; nt < 7; ++nt) {
                    int col = nt * 16 + l15;
                    if (col >= HD) continue;
                    #pragma unroll
                    for (int r = 0; r < 4; ++r)
                        atomicAdd(&gsum[gr[r] * HD + col], vals[nt][r]);
                }
            }
        } else {
            // transpose h into LDS (cols >=108 forced 0), zero pad cols 112..127
            #pragma unroll
            for (int nt = 0; nt < 7; ++nt) {
                int col = nt * 16 + l15;
                #pragma unroll
                for (int r = 0; r < 4; ++r) {
                    unsigned short hb = (col < HD) ? bf16_rne(vals[nt][r]) : 0;
                    s_t[wave][lg * 4 + r][col] = hb;
                }
            }
            #pragma unroll
            for (int p = 0; p < 2; ++p) {             // 16 rows x 8 uints (cols 112..127)
                int idx = p * 64 + lane;
                int row = idx >> 3, q = idx & 7;
                *(unsigned*)&s_t[wave][row][112 + q * 2] = 0u;
            }

            // h store: segs 0..13 = cols 0..111; seg 14 = zero pad at col 216
            #pragma unroll
            for (int p = 0; p < 4; ++p) {
                int seg = p * 4 + lg;
                if (seg < 14)
                    *(s16x8*)(hc + (size_t)(wrow + l15) * 224 + seg * 8) =
                        *(const s16x8*)&s_t[wave][l15][seg * 8];
                else if (seg == 14)
                    *(s16x8*)(hc + (size_t)(wrow + l15) * 224 + 216) =
                        *(const s16x8*)&s_t[wave][l15][112];
            }

            // pool: m = relu(h @ Wp + bp), A-fragments from LDS transpose
            f32x4 accp[7];
            #pragma unroll
            for (int nt = 0; nt < 7; ++nt) accp[nt] = (f32x4){0.f, 0.f, 0.f, 0.f};
            #pragma unroll
            for (int ks = 0; ks < 4; ++ks) {
                s16x8 a = *(const s16x8*)&s_t[wave][l15][ks * 32 + lg * 8];
                const unsigned short* wp = Wfp + ((size_t)(ks * 7) * 64 + lane) * 8;
                #pragma unroll
                for (int nt = 0; nt < 7; ++nt) {
                    s16x8 bfr = *(const s16x8*)(wp + (size_t)nt * 512);
                    accp[nt] = __builtin_amdgcn_mfma_f32_16x16x32_bf16(a, bfr, accp[nt], 0, 0, 0);
                }
            }
            // transpose m into LDS, then chunked aligned 16B stores
            #pragma unroll
            for (int nt = 0; nt < 7; ++nt) {
                int col = nt * 16 + l15;
                float bv = (col < HD) ? biasp[col] : 0.0f;
                #pragma unroll
                for (int r = 0; r < 4; ++r)
                    s_t[wave][lg * 4 + r][col] = bf16_rne(fmaxf(accp[nt][r] + bv, 0.0f));
            }
            #pragma unroll
            for (int p = 0; p < 4; ++p) {
                int seg = p * 4 + lg;
                if (seg < 14) {
                    int ch = seg >> 2, sub = seg & 3;
                    *(s16x8*)(m_out + ((size_t)ch * N_NODES + (wrow + l15)) * 32 + sub * 8) =
                        *(const s16x8*)&s_t[wave][l15][seg * 8];
                }
            }
        }
    }
}

template <int KSTEPS, int EPI>
__global__ __launch_bounds__(256) void gemm_k(
    const unsigned short* __restrict__ A, int strideA,
    const unsigned short* __restrict__ Wf, const float* __restrict__ bias,
    const unsigned short* __restrict__ Wfp, const float* __restrict__ biasp,
    unsigned short* __restrict__ hc, unsigned short* __restrict__ m_out,
    const int* __restrict__ gids, float* __restrict__ gsum) {
    gemm_body<KSTEPS, EPI, false>(blockIdx.x, A, strideA, Wf, bias, Wfp, biasp,
                                  hc, m_out, gids, gsum);
}

// ---------------------------------------------------------------------------
// mix: cscatter (depends only on bb from prep) || embed(f32)+pool1 (MFMA)
// ---------------------------------------------------------------------------
__global__ __launch_bounds__(256) void mix_k(
    const int* __restrict__ src, const int* __restrict__ dst,
    const int* __restrict__ bb, unsigned* __restrict__ ebuf,
    const float* __restrict__ feat,
    const unsigned short* __restrict__ Wf_emb, const float* __restrict__ bemb,
    const unsigned short* __restrict__ Wf_p1, const float* __restrict__ bp1,
    unsigned short* __restrict__ hc, unsigned short* __restrict__ m_out) {
    if (blockIdx.x < CB2) {
        cscatter_body(blockIdx.x, src, dst, bb, ebuf);
    } else {
        gemm_body<2, 0, true>(blockIdx.x - CB2, feat, FIN, Wf_emb, bemb,
                              Wf_p1, bp1, hc, m_out, nullptr, nullptr);
    }
}

// ---------------------------------------------------------------------------
// Chunked, software-pipelined aggregation. 4 lanes/node; 32-edge batches:
// each lane holds 8 consecutive csr entries (edges i+sub*8 .. i+sub*8+7),
// broadcast via __shfl -> 32 independent 16B gathers per batch; ~95% of
// nodes (deg<=32) finish in ONE L2 round trip. Edge order per node unchanged.
// ---------------------------------------------------------------------------
__global__ __launch_bounds__(256) void aggregate_k(
    const unsigned short* __restrict__ m,
    const int* __restrict__ rowp,
    const int* __restrict__ csr, unsigned short* __restrict__ hc) {
    int chunk = blockIdx.x & 3;
    int nblk  = blockIdx.x >> 2;
    int t = threadIdx.x, lane = t & 63, wave = t >> 6;
    int v = nblk * 64 + wave * 16 + (lane >> 2);
    if (v >= N_NODES) return;
    int sub = lane & 3;
    int co = sub * 8;                                 // within-chunk col offset
    int gcol = chunk * 32 + co;                       // global m/c column
    bool active = (gcol < 112);                       // chunk-3 upper half: mask only
    int grp = lane & ~3;
    const unsigned short* mc = m + (size_t)chunk * N_NODES * 32 + co;
    int beg = rowp[v], end = rowp[v + 1];
    float s[8] = {0.f, 0.f, 0.f, 0.f, 0.f, 0.f, 0.f, 0.f};

    int c[8];
    int i = beg;
    {
        int p = i + sub * 8;
        #pragma unroll
        for (int j = 0; j < 8; ++j) c[j] = (p + j < end) ? csr[p + j] : -1;
    }
    while (i < end) {
        int ni = i + 32;
        int n[8];
        #pragma unroll
        for (int j = 0; j < 8; ++j) n[j] = -1;
        if (ni < end) {                               // prefetch next batch early
            int p = ni + sub * 8;
            #pragma unroll
            for (int j = 0; j < 8; ++j) n[j] = (p + j < end) ? csr[p + j] : -1;
        }
        #pragma unroll
        for (int q4 = 0; q4 < 4; ++q4) {              // provider lane
            int svs[8];
            #pragma unroll
            for (int j = 0; j < 8; ++j) svs[j] = __shfl(c[j], grp + q4);
            #pragma unroll
            for (int j = 0; j < 8; ++j) {
                int sv = svs[j];
                if (sv >= 0 && active) {
                    s16x8 a = *(const s16x8*)(mc + (size_t)sv * 32);
                    #pragma unroll
                    for (int q = 0; q < 8; ++q) s[q] += bf16_to_f((unsigned short)a[q]);
                }
            }
        }
        #pragma unroll
        for (int j = 0; j < 8; ++j) c[j] = n[j];
        i = ni;
    }

    if (active) {
        int degv = end - beg;
        float inv = (degv > 0) ? 1.0f / (float)degv : 0.0f;
        unsigned short* dstp = hc + (size_t)v * 224 + HD + gcol;
        #pragma unroll
        for (int j2 = 0; j2 < 4; ++j2) {
            unsigned pk = (unsigned)bf16_rne(s[2 * j2] * inv) |
                          ((unsigned)bf16_rne(s[2 * j2 + 1] * inv) << 16);
            *(unsigned*)(dstp + 2 * j2) = pk;
        }
    }
}

__global__ void finalize_k(const float* __restrict__ gsum, const int* __restrict__ gcnt,
                           float* __restrict__ out) {
    int i = blockIdx.x * 256 + threadIdx.x;
    if (i < NG * HD) {
        int g = i / HD;
        int cnt = gcnt[g];
        float inv = (cnt > 0) ? 1.0f / (float)cnt : 0.0f;
        out[i] = gsum[i] * inv;
    }
}

// ---------------------------------------------------------------------------
extern "C" void kernel_launch(void* const* d_in, const int* in_sizes, int n_in,
                              void* d_out, int out_size, void* d_ws, size_t ws_size,
                              hipStream_t stream) {
    const float* feat = (const float*)d_in[0];
    const int* src  = (const int*)d_in[4];
    const int* dst  = (const int*)d_in[5];
    const int* gids = (const int*)d_in[6];
    const float* Wemb = (const float*)d_in[7];
    const float* bemb = (const float*)d_in[8];
    const float* Wp1  = (const float*)d_in[9];
    const float* bp1  = (const float*)d_in[10];
    const float* Wn1  = (const float*)d_in[11];
    const float* bn1  = (const float*)d_in[12];
    const float* Wp2  = (const float*)d_in[13];
    const float* bp2  = (const float*)d_in[14];
    const float* Wn2  = (const float*)d_in[15];
    const float* bn2  = (const float*)d_in[16];
    float* out = (float*)d_out;
    (void)in_sizes; (void)n_in; (void)out_size; (void)ws_size;

    char* ws = (char*)d_ws;
    size_t off = 0;
    auto carve = [&](size_t bytes) -> char* {
        char* p = ws + off;
        off = (off + bytes + 255) & ~(size_t)255;
        return p;
    };
    unsigned short* hc    = (unsigned short*)carve((size_t)N_NODES * 224 * 2);
    unsigned short* m_bf  = (unsigned short*)carve((size_t)4 * N_NODES * 32 * 2);
    unsigned short* Wf    = (unsigned short*)carve((size_t)24 * 7 * 512 * 2);
    int* rowp   = (int*)carve((size_t)(N_NODES + 1) * 4);
    int* csr    = (int*)carve((size_t)N_EDGES * 4);
    unsigned* ebuf = (unsigned*)carve((size_t)N_EDGES * 4);
    int* bb     = (int*)carve((size_t)NBIN * CB2 * 4);
    float* gsum = (float*)carve((size_t)NG * HD * 4);
    int*   gcnt = (int*)carve((size_t)NG * 4);

    // fused prep: repack + gsum zero + gcnt + coarse count
    prep_k<<<57 + CB2, 256, 0, stream>>>(Wemb, Wp1, Wn1, Wp2, Wn2, Wf,
                                         gsum, gids, gcnt, dst, bb);

    const int GB = (N_NODES / 16 + 3) / 4;           // 782 blocks x 4 waves
    const int AB = 4 * ((N_NODES + 63) / 64);        // 4 chunks x 782 node-blocks
    unsigned short* Wf_emb = Wf + (size_t)0  * 7 * 512;
    unsigned short* Wf_p1  = Wf + (size_t)2  * 7 * 512;
    unsigned short* Wf_n1  = Wf + (size_t)6  * 7 * 512;
    unsigned short* Wf_p2  = Wf + (size_t)13 * 7 * 512;
    unsigned short* Wf_n2  = Wf + (size_t)17 * 7 * 512;

    // cscatter || embed(f32)+pool1 in one dispatch
    mix_k<<<CB2 + GB, 256, 0, stream>>>(src, dst, bb, ebuf, feat, Wf_emb, bemb,
                                        Wf_p1, bp1, hc, m_bf);

    fine_k<<<NBIN, 512, 0, stream>>>(ebuf, bb, rowp, csr);

    // layer 1
    aggregate_k<<<AB, 256, 0, stream>>>(m_bf, rowp, csr, hc);
    gemm_k<7, 2><<<GB, 256, 0, stream>>>(hc, 224, Wf_n1, bn1, Wf_p2, bp2,
                                         hc, m_bf, nullptr, nullptr);
    // layer 2
    aggregate_k<<<AB, 256, 0, stream>>>(m_bf, rowp, csr, hc);
    gemm_k<7, 3><<<GB, 256, 0, stream>>>(hc, 224, Wf_n2, bn2, nullptr, nullptr,
                                         hc, nullptr, gids, gsum);

    finalize_k<<<(NG * HD + 255) / 256, 256, 0, stream>>>(gsum, gcnt, out);
}

// Round 21
// 149.963 us; speedup vs baseline: 1.0278x; 1.0278x over previous
//
#include <hip/hip_runtime.h>

#define N_NODES 50000
#define N_EDGES 800000
#define NG      128
#define FIN     64
#define HD      108
#define CB2     196         // coarse blocks: ceil(800000/4096), 16 edges/thread
#define NBIN    98          // coarse bins: ceil(50000/512), 512 nodes/bin

typedef __attribute__((ext_vector_type(8))) short s16x8;   // 8 bf16 = 4 VGPRs
typedef __attribute__((ext_vector_type(4))) float f32x4;

__device__ __forceinline__ unsigned short bf16_rne(float x) {
    unsigned u = __float_as_uint(x);
    u += 0x7FFFu + ((u >> 16) & 1u);
    return (unsigned short)(u >> 16);
}
__device__ __forceinline__ float bf16_to_f(unsigned u16) {
    return __uint_as_float(u16 << 16);
}

// ---------------------------------------------------------------------------
// Fused prep. block ranges: [0,42) wprep | [42,56) gsum zero | [56] gcnt |
// [57,253) coarse LDS-histogram count (writes bb, bin-major, bin = d>>9)
// Weight tiles (24 kst x 7 nt): emb 0..1 | p1 2..5 | n1 6..12 | p2 13..16 | n2 17..23
// ---------------------------------------------------------------------------
__global__ void prep_k(const float* __restrict__ W0, const float* __restrict__ W1,
                       const float* __restrict__ W2, const float* __restrict__ W3,
                       const float* __restrict__ W4, unsigned short* __restrict__ Wf,
                       float* __restrict__ gsum,
                       const int* __restrict__ gids, int* __restrict__ gcnt,
                       const int* __restrict__ dst, int* __restrict__ bb) {
    int b = blockIdx.x, t = threadIdx.x;
    if (b < 42) {                                     // weight repack, 1 tile/wave
        int tile = b * 4 + (t >> 6), lane = t & 63;
        if (tile < 168) {
            int kst = tile / 7, nt = tile % 7;
            const float* W; int Kr, ks;
            if (kst < 2)       { W = W0; Kr = 64;  ks = kst;      }
            else if (kst < 6)  { W = W1; Kr = 108; ks = kst - 2;  }
            else if (kst < 13) { W = W2; Kr = 216; ks = kst - 6;  }
            else if (kst < 17) { W = W3; Kr = 108; ks = kst - 13; }
            else               { W = W4; Kr = 216; ks = kst - 17; }
            int n = nt * 16 + (lane & 15);
            s16x8 o;
            #pragma unroll
            for (int j = 0; j < 8; ++j) {
                int k = ks * 32 + (lane >> 4) * 8 + j;
                float v = (k < Kr && n < HD) ? W[k * HD + n] : 0.0f;
                o[j] = (short)bf16_rne(v);
            }
            *(s16x8*)(Wf + (size_t)tile * 512 + lane * 8) = o;
        }
    } else if (b < 56) {                              // gsum = 0
        int i = (b - 42) * 256 + t;
        if (i < NG * HD / 4) ((int4*)gsum)[i] = (int4){0, 0, 0, 0};
    } else if (b == 56) {                             // per-graph counts (sorted)
        int g = t;
        if (g < NG) {
            int lo = 0, hi = N_NODES;
            while (lo < hi) { int mid = (lo + hi) >> 1; if (gids[mid] < g) lo = mid + 1; else hi = mid; }
            int s = lo;
            lo = s; hi = N_NODES;
            while (lo < hi) { int mid = (lo + hi) >> 1; if (gids[mid] < g + 1) lo = mid + 1; else hi = mid; }
            gcnt[g] = lo - s;
        }
    } else {                                          // coarse count, 16 e/thread
        __shared__ int bins[NBIN];
        int cb = b - 57;
        if (t < NBIN) bins[t] = 0;
        __syncthreads();
        #pragma unroll
        for (int k = 0; k < 16; ++k) {
            int e = cb * 4096 + k * 256 + t;
            if (e < N_EDGES) atomicAdd(&bins[dst[e] >> 9], 1);
        }
        __syncthreads();
        if (t < NBIN) bb[t * CB2 + cb] = bins[t];
    }
}

// ---------------------------------------------------------------------------
// cscatter body: scatter packed (src | dlocal<<16) into coarse buckets.
// Cursors computed IN-BLOCK from bb (bin-major). No global atomics.
// ---------------------------------------------------------------------------
__device__ __forceinline__ void cscatter_body(
    int b, const int* __restrict__ src, const int* __restrict__ dst,
    const int* __restrict__ bb, unsigned* __restrict__ ebuf) {
    __shared__ int cur[NBIN];
    __shared__ int btot[NBIN];
    __shared__ int sc[128];
    int t = threadIdx.x;
    int myv = 0;
    if (t < NBIN) {                                   // thread t owns bin t
        int pre = 0, tot = 0;
        const int* row = bb + t * CB2;
        for (int b2 = 0; b2 < CB2; ++b2) {
            int v = row[b2];
            tot += v;
            if (b2 < b) pre += v;
        }
        btot[t] = tot;
        cur[t] = pre;                                 // within-bin offset
        myv = tot;
    }
    __syncthreads();
    if (t < 128) {                                    // 2-wave inclusive scan
        int v = (t < NBIN) ? btot[t] : 0;
        int x = v;
        #pragma unroll
        for (int off = 1; off < 64; off <<= 1) {
            int y = __shfl_up(x, off);
            if ((t & 63) >= off) x += y;
        }
        sc[t] = x;
    }
    __syncthreads();
    if (t < NBIN) {
        int incl = sc[t] + ((t >= 64) ? sc[63] : 0);
        cur[t] += incl - myv;                         // + exclusive bin start
    }
    __syncthreads();
    #pragma unroll
    for (int k = 0; k < 16; ++k) {
        int e = b * 4096 + k * 256 + t;
        if (e < N_EDGES) {
            int d = dst[e];
            int slot = atomicAdd(&cur[d >> 9], 1);
            ebuf[slot] = (unsigned)src[e] | ((unsigned)(d & 511) << 16);
        }
    }
}

// ---------------------------------------------------------------------------
// fine: per coarse bucket (<=512 nodes). Bucket [begin,end) computed in-block
// by reducing bb. Then LDS histogram + scan -> rowp + csr scatter.
// ---------------------------------------------------------------------------
__global__ __launch_bounds__(1024) void fine_k(
    const unsigned* __restrict__ ebuf, const int* __restrict__ bb,
    int* __restrict__ rowp, int* __restrict__ csr) {
    __shared__ int fb[512];
    __shared__ int s_w[8];
    __shared__ int red1[16], red2[16];
    int t = threadIdx.x, lane = t & 63, wid = t >> 6;
    int bin = blockIdx.x;

    // ---- compute begin/end from bb ----
    int lim1 = bin * CB2, lim2 = lim1 + CB2;
    int s1 = 0, s2 = 0;
    for (int i = t; i < lim2; i += 1024) {
        int v = bb[i];
        if (i < lim1) s1 += v; else s2 += v;
    }
    #pragma unroll
    for (int off = 32; off >= 1; off >>= 1) {
        s1 += __shfl_xor(s1, off);
        s2 += __shfl_xor(s2, off);
    }
    if (lane == 0) { red1[wid] = s1; red2[wid] = s2; }
    __syncthreads();
    if (t == 0) {
        int a = 0, c = 0;
        #pragma unroll
        for (int w = 0; w < 16; ++w) { a += red1[w]; c += red2[w]; }
        red1[0] = a; red2[0] = c;
    }
    __syncthreads();
    int begin = red1[0], end = begin + red2[0];

    // ---- histogram over 512 local nodes ----
    if (t < 512) fb[t] = 0;
    __syncthreads();
    for (int i = begin + t; i < end; i += 1024)
        atomicAdd(&fb[ebuf[i] >> 16], 1);
    __syncthreads();
    if (t < 512) {
        int v = fb[t];
        int x = v;
        #pragma unroll
        for (int off = 1; off < 64; off <<= 1) {
            int y = __shfl_up(x, off);
            if (lane >= off) x += y;
        }
        if (lane == 63) s_w[wid] = x;
        __syncthreads();
        if (t < 8) {
            int y = s_w[t];
            #pragma unroll
            for (int off = 1; off < 8; off <<= 1) {
                int z = __shfl_up(y, off);
                if (t >= off) y += z;
            }
            s_w[t] = y;
        }
        __syncthreads();
        int ex = (wid ? s_w[wid - 1] : 0) + x - v;    // exclusive within bucket
        int node = bin * 512 + t;
        if (node < N_NODES) rowp[node] = begin + ex;
        if (bin == NBIN - 1 && t == 0) rowp[N_NODES] = N_EDGES;
        __syncthreads();
        fb[t] = ex;                                   // reuse as cursor
    } else {
        __syncthreads();
        __syncthreads();
        __syncthreads();
    }
    __syncthreads();
    for (int i = begin + t; i < end; i += 1024) {
        unsigned p = ebuf[i];
        int slot = atomicAdd(&fb[p >> 16], 1);
        csr[begin + slot] = (int)(p & 0xFFFFu);
    }
}

// ---------------------------------------------------------------------------
// Shared GEMM body. One wave = 16 nodes x 112 cols.
// EPI: 0=embed+pool, 2=apply+pool, 3=apply-final(graph-sum atomics).
// AF32: A operand is f32 (feat) -> convert to bf16 in-register.
// For EPI!=0, A-fragments ks<4 are staged into s_t for the LDS residual read.
// Epilogue maintains the hc col-216..223 zero pad (seg 14).
// m layout: CHUNKED m[ch][node][32] bf16, ch = col/32.
// ---------------------------------------------------------------------------
template <int KSTEPS, int EPI, bool AF32>
__device__ __forceinline__ void gemm_body(
    int blk,
    const void* __restrict__ Aptr, int strideA,
    const unsigned short* __restrict__ Wf, const float* __restrict__ bias,
    const unsigned short* __restrict__ Wfp, const float* __restrict__ biasp,
    unsigned short* __restrict__ hc, unsigned short* __restrict__ m_out,
    const int* __restrict__ gids, float* __restrict__ gsum) {
    __shared__ unsigned short s_t[4][16][136];
    int t = threadIdx.x, lane = t & 63, wave = t >> 6;
    int wrow = (blk * 4 + wave) * 16;
    if (wrow < N_NODES) {
        int l15 = lane & 15, lg = lane >> 4;

        f32x4 acc[7];
        #pragma unroll
        for (int nt = 0; nt < 7; ++nt) acc[nt] = (f32x4){0.f, 0.f, 0.f, 0.f};

        #pragma unroll
        for (int ks = 0; ks < KSTEPS; ++ks) {
            s16x8 a;
            if (AF32) {
                const float* arow = (const float*)Aptr + (size_t)(wrow + l15) * strideA + lg * 8 + ks * 32;
                float4 f0 = *(const float4*)arow;
                float4 f1 = *(const float4*)(arow + 4);
                a[0] = (short)bf16_rne(f0.x); a[1] = (short)bf16_rne(f0.y);
                a[2] = (short)bf16_rne(f0.z); a[3] = (short)bf16_rne(f0.w);
                a[4] = (short)bf16_rne(f1.x); a[5] = (short)bf16_rne(f1.y);
                a[6] = (short)bf16_rne(f1.z); a[7] = (short)bf16_rne(f1.w);
            } else {
                const unsigned short* arow = (const unsigned short*)Aptr + (size_t)(wrow + l15) * strideA + lg * 8;
                a = *(const s16x8*)(arow + ks * 32);
            }
            if (EPI != 0 && ks < 4)                   // stage h for residual
                *(s16x8*)&s_t[wave][l15][ks * 32 + lg * 8] = a;
            const unsigned short* wp = Wf + ((size_t)(ks * 7) * 64 + lane) * 8;
            #pragma unroll
            for (int nt = 0; nt < 7; ++nt) {
                s16x8 bfr = *(const s16x8*)(wp + (size_t)nt * 512);
                acc[nt] = __builtin_amdgcn_mfma_f32_16x16x32_bf16(a, bfr, acc[nt], 0, 0, 0);
            }
        }

        // D layout: col = nt*16 + l15, row(local) = lg*4 + r
        float vals[7][4];
        if (EPI == 0) {                               // embed: + bias
            #pragma unroll
            for (int nt = 0; nt < 7; ++nt) {
                int col = nt * 16 + l15;
                float bv = (col < HD) ? bias[col] : 0.0f;
                #pragma unroll
                for (int r = 0; r < 4; ++r) vals[nt][r] = acc[nt][r] + bv;
            }
        } else {                                      // apply: norm + residual
            float ss[4] = {0.f, 0.f, 0.f, 0.f};
            #pragma unroll
            for (int nt = 0; nt < 7; ++nt) {
                int col = nt * 16 + l15;
                bool valid = (col < HD);
                float bv = valid ? bias[col] : 0.0f;
                #pragma unroll
                for (int r = 0; r < 4; ++r) {
                    float v = valid ? (acc[nt][r] + bv) : 0.0f;
                    vals[nt][r] = v;
                    ss[r] += v * v;
                }
            }
            #pragma unroll
            for (int r = 0; r < 4; ++r) {
                ss[r] += __shfl_xor(ss[r], 1);
                ss[r] += __shfl_xor(ss[r], 2);
                ss[r] += __shfl_xor(ss[r], 4);
                ss[r] += __shfl_xor(ss[r], 8);
            }
            float rn[4];
            #pragma unroll
            for (int r = 0; r < 4; ++r) rn[r] = 1.0f / fmaxf(sqrtf(ss[r]), 1e-12f);
            #pragma unroll
            for (int nt = 0; nt < 7; ++nt) {
                int col = nt * 16 + l15;
                bool valid = (col < HD);
                #pragma unroll
                for (int r = 0; r < 4; ++r) {
                    float hv = valid ? bf16_to_f(s_t[wave][lg * 4 + r][col]) : 0.0f;
                    vals[nt][r] = hv + fmaxf(vals[nt][r] * rn[r], 0.0f);
                }
            }
        }

        if (EPI == 3) {                               // graph-mean accumulation
            int g0 = gids[wrow], g15 = gids[wrow + 15];
            if (g0 == g15) {
                #pragma unroll
                for (int nt = 0; nt < 7; ++nt) {
                    int col = nt * 16 + l15;
                    float cs = vals[nt][0] + vals[nt][1] + vals[nt][2] + vals[nt][3];
                    cs += __shfl_xor(cs, 16);
                    cs += __shfl_xor(cs, 32);
                    if (lane < 16 && col < HD) atomicAdd(&gsum[g0 * HD + col], cs);
                }
            } else {
                int gr[4];
                #pragma unroll
                for (int r = 0; r < 4; ++r) gr[r] = gids[wrow + lg * 4 + r];
                #pragma unroll
                for (int nt = 0; nt < 7; ++nt) {
                    int col = nt * 16 + l15;
                    if (col >= HD) continue;
                    #pragma unroll
                    for (int r = 0; r < 4; ++r)
                        atomicAdd(&gsum[gr[r] * HD + col], vals[nt][r]);
                }
            }
        } else {
            // transpose h into LDS (cols >=108 forced 0), zero pad cols 112..127
            #pragma unroll
            for (int nt = 0; nt < 7; ++nt) {
                int col = nt * 16 + l15;
                #pragma unroll
                for (int r = 0; r < 4; ++r) {
                    unsigned short hb = (col < HD) ? bf16_rne(vals[nt][r]) : 0;
                    s_t[wave][lg * 4 + r][col] = hb;
                }
            }
            #pragma unroll
            for (int p = 0; p < 2; ++p) {             // 16 rows x 8 uints (cols 112..127)
                int idx = p * 64 + lane;
                int row = idx >> 3, q = idx & 7;
                *(unsigned*)&s_t[wave][row][112 + q * 2] = 0u;
            }

            // h store: segs 0..13 = cols 0..111; seg 14 = zero pad at col 216
            #pragma unroll
            for (int p = 0; p < 4; ++p) {
                int seg = p * 4 + lg;
                if (seg < 14)
                    *(s16x8*)(hc + (size_t)(wrow + l15) * 224 + seg * 8) =
                        *(const s16x8*)&s_t[wave][l15][seg * 8];
                else if (seg == 14)
                    *(s16x8*)(hc + (size_t)(wrow + l15) * 224 + 216) =
                        *(const s16x8*)&s_t[wave][l15][112];
            }

            // pool: m = relu(h @ Wp + bp), A-fragments from LDS transpose
            f32x4 accp[7];
            #pragma unroll
            for (int nt = 0; nt < 7; ++nt) accp[nt] = (f32x4){0.f, 0.f, 0.f, 0.f};
            #pragma unroll
            for (int ks = 0; ks < 4; ++ks) {
                s16x8 a = *(const s16x8*)&s_t[wave][l15][ks * 32 + lg * 8];
                const unsigned short* wp = Wfp + ((size_t)(ks * 7) * 64 + lane) * 8;
                #pragma unroll
                for (int nt = 0; nt < 7; ++nt) {
                    s16x8 bfr = *(const s16x8*)(wp + (size_t)nt * 512);
                    accp[nt] = __builtin_amdgcn_mfma_f32_16x16x32_bf16(a, bfr, accp[nt], 0, 0, 0);
                }
            }
            // transpose m into LDS, then chunked aligned 16B stores
            #pragma unroll
            for (int nt = 0; nt < 7; ++nt) {
                int col = nt * 16 + l15;
                float bv = (col < HD) ? biasp[col] : 0.0f;
                #pragma unroll
                for (int r = 0; r < 4; ++r)
                    s_t[wave][lg * 4 + r][col] = bf16_rne(fmaxf(accp[nt][r] + bv, 0.0f));
            }
            #pragma unroll
            for (int p = 0; p < 4; ++p) {
                int seg = p * 4 + lg;
                if (seg < 14) {
                    int ch = seg >> 2, sub = seg & 3;
                    *(s16x8*)(m_out + ((size_t)ch * N_NODES + (wrow + l15)) * 32 + sub * 8) =
                        *(const s16x8*)&s_t[wave][l15][seg * 8];
                }
            }
        }
    }
}

template <int KSTEPS, int EPI>
__global__ __launch_bounds__(256) void gemm_k(
    const unsigned short* __restrict__ A, int strideA,
    const unsigned short* __restrict__ Wf, const float* __restrict__ bias,
    const unsigned short* __restrict__ Wfp, const float* __restrict__ biasp,
    unsigned short* __restrict__ hc, unsigned short* __restrict__ m_out,
    const int* __restrict__ gids, float* __restrict__ gsum) {
    gemm_body<KSTEPS, EPI, false>(blockIdx.x, A, strideA, Wf, bias, Wfp, biasp,
                                  hc, m_out, gids, gsum);
}

// ---------------------------------------------------------------------------
// mix: cscatter (depends only on bb from prep) || embed(f32)+pool1 (MFMA)
// ---------------------------------------------------------------------------
__global__ __launch_bounds__(256) void mix_k(
    const int* __restrict__ src, const int* __restrict__ dst,
    const int* __restrict__ bb, unsigned* __restrict__ ebuf,
    const float* __restrict__ feat,
    const unsigned short* __restrict__ Wf_emb, const float* __restrict__ bemb,
    const unsigned short* __restrict__ Wf_p1, const float* __restrict__ bp1,
    unsigned short* __restrict__ hc, unsigned short* __restrict__ m_out) {
    if (blockIdx.x < CB2) {
        cscatter_body(blockIdx.x, src, dst, bb, ebuf);
    } else {
        gemm_body<2, 0, true>(blockIdx.x - CB2, feat, FIN, Wf_emb, bemb,
                              Wf_p1, bp1, hc, m_out, nullptr, nullptr);
    }
}

// ---------------------------------------------------------------------------
// Chunked, software-pipelined aggregation. 4 lanes/node; 16-edge batches.
// ---------------------------------------------------------------------------
__global__ __launch_bounds__(256) void aggregate_k(
    const unsigned short* __restrict__ m,
    const int* __restrict__ rowp,
    const int* __restrict__ csr, unsigned short* __restrict__ hc) {
    int chunk = blockIdx.x & 3;
    int nblk  = blockIdx.x >> 2;
    int t = threadIdx.x, lane = t & 63, wave = t >> 6;
    int v = nblk * 64 + wave * 16 + (lane >> 2);
    if (v >= N_NODES) return;
    int sub = lane & 3;
    int co = sub * 8;                                 // within-chunk col offset
    int gcol = chunk * 32 + co;                       // global m/c column
    bool active = (gcol < 112);                       // chunk-3 upper half: mask only
    int grp = lane & ~3;
    const unsigned short* mc = m + (size_t)chunk * N_NODES * 32 + co;
    int beg = rowp[v], end = rowp[v + 1];
    float s[8] = {0.f, 0.f, 0.f, 0.f, 0.f, 0.f, 0.f, 0.f};

    int i = beg;
    int c0, c1, c2, c3;
    {
        int p = i + sub * 4;
        c0 = (p < end) ? csr[p] : -1;
        c1 = (p + 1 < end) ? csr[p + 1] : -1;
        c2 = (p + 2 < end) ? csr[p + 2] : -1;
        c3 = (p + 3 < end) ? csr[p + 3] : -1;
    }
    while (i < end) {
        int ni = i + 16;
        int n0 = -1, n1 = -1, n2 = -1, n3 = -1;
        if (ni < end) {                               // prefetch next batch early
            int p = ni + sub * 4;
            n0 = (p < end) ? csr[p] : -1;
            n1 = (p + 1 < end) ? csr[p + 1] : -1;
            n2 = (p + 2 < end) ? csr[p + 2] : -1;
            n3 = (p + 3 < end) ? csr[p + 3] : -1;
        }
        #pragma unroll
        for (int q4 = 0; q4 < 4; ++q4) {              // provider lane
            int sv0 = __shfl(c0, grp + q4);
            int sv1 = __shfl(c1, grp + q4);
            int sv2 = __shfl(c2, grp + q4);
            int sv3 = __shfl(c3, grp + q4);
            int svs[4] = {sv0, sv1, sv2, sv3};
            #pragma unroll
            for (int j = 0; j < 4; ++j) {
                int sv = svs[j];
                if (sv >= 0 && active) {
                    s16x8 a = *(const s16x8*)(mc + (size_t)sv * 32);
                    #pragma unroll
                    for (int q = 0; q < 8; ++q) s[q] += bf16_to_f((unsigned short)a[q]);
                }
            }
        }
        c0 = n0; c1 = n1; c2 = n2; c3 = n3; i = ni;
    }

    if (active) {
        int degv = end - beg;
        float inv = (degv > 0) ? 1.0f / (float)degv : 0.0f;
        unsigned short* dstp = hc + (size_t)v * 224 + HD + gcol;
        #pragma unroll
        for (int j2 = 0; j2 < 4; ++j2) {
            unsigned pk = (unsigned)bf16_rne(s[2 * j2] * inv) |
                          ((unsigned)bf16_rne(s[2 * j2 + 1] * inv) << 16);
            *(unsigned*)(dstp + 2 * j2) = pk;
        }
    }
}

__global__ void finalize_k(const float* __restrict__ gsum, const int* __restrict__ gcnt,
                           float* __restrict__ out) {
    int i = blockIdx.x * 256 + threadIdx.x;
    if (i < NG * HD) {
        int g = i / HD;
        int cnt = gcnt[g];
        float inv = (cnt > 0) ? 1.0f / (float)cnt : 0.0f;
        out[i] = gsum[i] * inv;
    }
}

// ---------------------------------------------------------------------------
extern "C" void kernel_launch(void* const* d_in, const int* in_sizes, int n_in,
                              void* d_out, int out_size, void* d_ws, size_t ws_size,
                              hipStream_t stream) {
    const float* feat = (const float*)d_in[0];
    const int* src  = (const int*)d_in[4];
    const int* dst  = (const int*)d_in[5];
    const int* gids = (const int*)d_in[6];
    const float* Wemb = (const float*)d_in[7];
    const float* bemb = (const float*)d_in[8];
    const float* Wp1  = (const float*)d_in[9];
    const float* bp1  = (const float*)d_in[10];
    const float* Wn1  = (const float*)d_in[11];
    const float* bn1  = (const float*)d_in[12];
    const float* Wp2  = (const float*)d_in[13];
    const float* bp2  = (const float*)d_in[14];
    const float* Wn2  = (const float*)d_in[15];
    const float* bn2  = (const float*)d_in[16];
    float* out = (float*)d_out;
    (void)in_sizes; (void)n_in; (void)out_size; (void)ws_size;

    char* ws = (char*)d_ws;
    size_t off = 0;
    auto carve = [&](size_t bytes) -> char* {
        char* p = ws + off;
        off = (off + bytes + 255) & ~(size_t)255;
        return p;
    };
    unsigned short* hc    = (unsigned short*)carve((size_t)N_NODES * 224 * 2);
    unsigned short* m_bf  = (unsigned short*)carve((size_t)4 * N_NODES * 32 * 2);
    unsigned short* Wf    = (unsigned short*)carve((size_t)24 * 7 * 512 * 2);
    int* rowp   = (int*)carve((size_t)(N_NODES + 1) * 4);
    int* csr    = (int*)carve((size_t)N_EDGES * 4);
    unsigned* ebuf = (unsigned*)carve((size_t)N_EDGES * 4);
    int* bb     = (int*)carve((size_t)NBIN * CB2 * 4);
    float* gsum = (float*)carve((size_t)NG * HD * 4);
    int*   gcnt = (int*)carve((size_t)NG * 4);

    // fused prep: repack + gsum zero + gcnt + coarse count
    prep_k<<<57 + CB2, 256, 0, stream>>>(Wemb, Wp1, Wn1, Wp2, Wn2, Wf,
                                         gsum, gids, gcnt, dst, bb);

    const int GB = (N_NODES / 16 + 3) / 4;           // 782 blocks x 4 waves
    const int AB = 4 * ((N_NODES + 63) / 64);        // 4 chunks x 782 node-blocks
    unsigned short* Wf_emb = Wf + (size_t)0  * 7 * 512;
    unsigned short* Wf_p1  = Wf + (size_t)2  * 7 * 512;
    unsigned short* Wf_n1  = Wf + (size_t)6  * 7 * 512;
    unsigned short* Wf_p2  = Wf + (size_t)13 * 7 * 512;
    unsigned short* Wf_n2  = Wf + (size_t)17 * 7 * 512;

    // cscatter || embed(f32)+pool1 in one dispatch
    mix_k<<<CB2 + GB, 256, 0, stream>>>(src, dst, bb, ebuf, feat, Wf_emb, bemb,
                                        Wf_p1, bp1, hc, m_bf);

    fine_k<<<NBIN, 1024, 0, stream>>>(ebuf, bb, rowp, csr);

    // layer 1
    aggregate_k<<<AB, 256, 0, stream>>>(m_bf, rowp, csr, hc);
    gemm_k<7, 2><<<GB, 256, 0, stream>>>(hc, 224, Wf_n1, bn1, Wf_p2, bp2,
                                         hc, m_bf, nullptr, nullptr);
    // layer 2
    aggregate_k<<<AB, 256, 0, stream>>>(m_bf, rowp, csr, hc);
    gemm_k<7, 3><<<GB, 256, 0, stream>>>(hc, 224, Wf_n2, bn2, nullptr, nullptr,
                                         hc, nullptr, gids, gsum);

    finalize_k<<<(NG * HD + 255) / 256, 256, 0, stream>>>(gsum, gcnt, out);
}